// Round 1
// baseline (240.375 us; speedup 1.0000x reference)
//
#include <hip/hip_runtime.h>
#include <stdint.h>
#include <stddef.h>

// Problem constants (fixed by setup_inputs)
#define NB   2      // batch
#define NL   2048   // seq len
#define ND   512    // model dim
#define NH   8      // heads
#define DH   64     // dim head

typedef __attribute__((ext_vector_type(8))) short bf16x8;
typedef __attribute__((ext_vector_type(4))) float f32x4;

__device__ __forceinline__ unsigned short f2bf(float f) {
  union { float f; unsigned int u; } c; c.f = f;
  unsigned int u = c.u;
  unsigned int r = u + 0x7fffu + ((u >> 16) & 1u);
  return (unsigned short)(r >> 16);
}

// ---------------------------------------------------------------------------
// Generic 128x128-tile bf16-MFMA GEMM:  C[m][n] = sum_k A[m][k] * B[n][k]
// A: [M x K] f32 row-major, B: [N x K] f32 row-major (i.e. B^T GEMM).
// MODE 0: scatter output as bf16 into q/k/v buffers laid out [B,H,L,DH].
// MODE 1: output f32 + bias -> out [M x N] row-major (N=512).
// ---------------------------------------------------------------------------
template<int MODE>
__global__ __launch_bounds__(256, 2) void gemm_bf16_kernel(
    const float* __restrict__ A, const float* __restrict__ Bm,
    const float* __restrict__ bias,
    unsigned short* __restrict__ qo, unsigned short* __restrict__ ko,
    unsigned short* __restrict__ vo, float* __restrict__ out, int K)
{
  const int tid  = threadIdx.x;
  const int wid  = tid >> 6;
  const int lane = tid & 63;
  const int quad = lane >> 4;
  const int l15  = lane & 15;
  const int m0 = blockIdx.x * 128;
  const int n0 = blockIdx.y * 128;
  const int wm = (wid >> 1) * 64;
  const int wn = (wid & 1) * 64;

  __shared__ __align__(16) unsigned short As[128][48];  // 48 = 32 + 16 pad (96B rows)
  __shared__ __align__(16) unsigned short Bs[128][48];

  f32x4 acc[4][4];
  for (int a = 0; a < 4; ++a)
    for (int b = 0; b < 4; ++b)
      for (int z = 0; z < 4; ++z) acc[a][b][z] = 0.f;

  const int srow = tid >> 1;   // 0..127
  const int sseg = tid & 1;    // 16-float segment within 32-float K-step

  for (int k0 = 0; k0 < K; k0 += 32) {
    // ---- stage A tile (f32 -> bf16) ----
    {
      const float4* src = (const float4*)(A + (size_t)(m0 + srow) * K + k0 + sseg * 16);
      float4 f0 = src[0], f1 = src[1], f2 = src[2], f3 = src[3];
      uint32_t p0 = f2bf(f0.x) | ((uint32_t)f2bf(f0.y) << 16);
      uint32_t p1 = f2bf(f0.z) | ((uint32_t)f2bf(f0.w) << 16);
      uint32_t p2 = f2bf(f1.x) | ((uint32_t)f2bf(f1.y) << 16);
      uint32_t p3 = f2bf(f1.z) | ((uint32_t)f2bf(f1.w) << 16);
      uint32_t p4 = f2bf(f2.x) | ((uint32_t)f2bf(f2.y) << 16);
      uint32_t p5 = f2bf(f2.z) | ((uint32_t)f2bf(f2.w) << 16);
      uint32_t p6 = f2bf(f3.x) | ((uint32_t)f2bf(f3.y) << 16);
      uint32_t p7 = f2bf(f3.z) | ((uint32_t)f2bf(f3.w) << 16);
      uint4* dst = (uint4*)&As[srow][sseg * 16];
      dst[0] = make_uint4(p0, p1, p2, p3);
      dst[1] = make_uint4(p4, p5, p6, p7);
    }
    // ---- stage B tile ----
    {
      const float4* src = (const float4*)(Bm + (size_t)(n0 + srow) * K + k0 + sseg * 16);
      float4 f0 = src[0], f1 = src[1], f2 = src[2], f3 = src[3];
      uint32_t p0 = f2bf(f0.x) | ((uint32_t)f2bf(f0.y) << 16);
      uint32_t p1 = f2bf(f0.z) | ((uint32_t)f2bf(f0.w) << 16);
      uint32_t p2 = f2bf(f1.x) | ((uint32_t)f2bf(f1.y) << 16);
      uint32_t p3 = f2bf(f1.z) | ((uint32_t)f2bf(f1.w) << 16);
      uint32_t p4 = f2bf(f2.x) | ((uint32_t)f2bf(f2.y) << 16);
      uint32_t p5 = f2bf(f2.z) | ((uint32_t)f2bf(f2.w) << 16);
      uint32_t p6 = f2bf(f3.x) | ((uint32_t)f2bf(f3.y) << 16);
      uint32_t p7 = f2bf(f3.z) | ((uint32_t)f2bf(f3.w) << 16);
      uint4* dst = (uint4*)&Bs[srow][sseg * 16];
      dst[0] = make_uint4(p0, p1, p2, p3);
      dst[1] = make_uint4(p4, p5, p6, p7);
    }
    __syncthreads();

    bf16x8 af[4], bfr[4];
#pragma unroll
    for (int mb = 0; mb < 4; ++mb)
      af[mb] = *(const bf16x8*)&As[wm + mb * 16 + l15][quad * 8];
#pragma unroll
    for (int nb = 0; nb < 4; ++nb)
      bfr[nb] = *(const bf16x8*)&Bs[wn + nb * 16 + l15][quad * 8];
#pragma unroll
    for (int mb = 0; mb < 4; ++mb)
#pragma unroll
      for (int nb = 0; nb < 4; ++nb)
        acc[mb][nb] = __builtin_amdgcn_mfma_f32_16x16x32_bf16(af[mb], bfr[nb], acc[mb][nb], 0, 0, 0);
    __syncthreads();
  }

  // ---- epilogue ----
#pragma unroll
  for (int mb = 0; mb < 4; ++mb) {
#pragma unroll
    for (int r = 0; r < 4; ++r) {
      int m  = m0 + wm + mb * 16 + quad * 4 + r;
      int bb = m >> 11;         // m / 2048
      int ll = m & 2047;
#pragma unroll
      for (int nb = 0; nb < 4; ++nb) {
        int n = n0 + wn + nb * 16 + l15;
        float v = acc[mb][nb][r];
        if (MODE == 0) {
          int s  = n >> 9;        // 0=q, 1=k, 2=v
          int hh = (n >> 6) & 7;
          int dh = n & 63;
          unsigned short* dst = (s == 0) ? qo : ((s == 1) ? ko : vo);
          dst[(((size_t)bb * NH + hh) * NL + ll) * DH + dh] = f2bf(v);
        } else {
          out[((size_t)bb * NL + ll) * ND + n] = v + bias[n];
        }
      }
    }
  }
}

// ---------------------------------------------------------------------------
// Flash attention with Gaussian spatial bias.
// Block = 256 threads (4 waves); each block handles 64 query rows of one (b,h).
// Wave w owns query rows [w*16, w*16+16). j-tiles of 64.
// q/k/v: bf16 [B,H,L,DH]. Output: f32 [B, L, H*DH].
// ---------------------------------------------------------------------------
__global__ __launch_bounds__(256, 2) void flash_kernel(
    const unsigned short* __restrict__ qb, const unsigned short* __restrict__ kb,
    const unsigned short* __restrict__ vb, const float* __restrict__ positions,
    const float* __restrict__ log_sigma, const float* __restrict__ gbias_p,
    const int* __restrict__ ns_p, float* __restrict__ attn_out)
{
  const int it = blockIdx.x;      // 0..31 (q tile)
  const int h  = blockIdx.y;
  const int b  = blockIdx.z;
  const int i0 = it * 64;
  const int Ls = ns_p[0];
  const float gb = gbias_p[0];
  const float sig = __expf(log_sigma[h]);
  const float inv2s2 = 0.5f / (sig * sig);
  const float scale = 0.125f;     // 64^-0.5

  const int tid  = threadIdx.x;
  const int wid  = tid >> 6;
  const int lane = tid & 63;
  const int quad = lane >> 4;
  const int l15  = lane & 15;

  __shared__ __align__(16) unsigned short Qs[64][72];
  __shared__ __align__(16) unsigned short Ks[64][72];
  __shared__ __align__(16) unsigned short Vt[64][72];   // transposed: [dh][j]
  __shared__ __align__(16) unsigned short Ps[64][72];
  __shared__ float pix[64], piy[64], pjx[64], pjy[64];

  const unsigned short* qbase = qb + (((size_t)b * NH + h) * NL + i0) * DH;
  const unsigned short* kbase = kb + (((size_t)b * NH + h) * NL) * DH;
  const unsigned short* vbase = vb + (((size_t)b * NH + h) * NL) * DH;

  // stage Q tile (64 x 64 bf16 = 512 16B chunks)
  for (int c = tid; c < 512; c += 256) {
    int row = c >> 3, off = c & 7;
    *(uint4*)&Qs[row][off * 8] = *(const uint4*)(qbase + row * DH + off * 8);
  }
  if (tid < 64) {
    int i = i0 + tid;
    float px = 0.f, py = 0.f;
    if (i < Ls) {
      px = positions[((size_t)b * Ls + i) * 2 + 0];
      py = positions[((size_t)b * Ls + i) * 2 + 1];
    }
    pix[tid] = px; piy[tid] = py;
  }

  // online softmax state: row = i0 + wid*16 + quad*4 + r  (replicated over quad's 16 lanes)
  float mrow[4], lrow[4];
  f32x4 accO[4];
#pragma unroll
  for (int r = 0; r < 4; ++r) { mrow[r] = -1e30f; lrow[r] = 0.f; }
#pragma unroll
  for (int nb = 0; nb < 4; ++nb)
    for (int z = 0; z < 4; ++z) accO[nb][z] = 0.f;

  for (int jt = 0; jt < NL / 64; ++jt) {
    const int j0 = jt * 64;
    __syncthreads();   // previous iteration's reads of Ks/Vt done; Q staged (first iter)

    // stage K tile
    for (int c = tid; c < 512; c += 256) {
      int row = c >> 3, off = c & 7;
      *(uint4*)&Ks[row][off * 8] = *(const uint4*)(kbase + (size_t)(j0 + row) * DH + off * 8);
    }
    // stage V tile transposed
    for (int c = tid; c < 512; c += 256) {
      int row = c >> 3, off = c & 7;
      uint4 val = *(const uint4*)(vbase + (size_t)(j0 + row) * DH + off * 8);
      unsigned short* ev = (unsigned short*)&val;
#pragma unroll
      for (int z = 0; z < 8; ++z) Vt[off * 8 + z][row] = ev[z];
    }
    if (tid < 64) {
      int j = j0 + tid;
      float px = 0.f, py = 0.f;
      if (j < Ls) {
        px = positions[((size_t)b * Ls + j) * 2 + 0];
        py = positions[((size_t)b * Ls + j) * 2 + 1];
      }
      pjx[tid] = px; pjy[tid] = py;
    }
    __syncthreads();

    // S = Q K^T  (wave strip: rows wid*16..+16, all 64 cols)
    f32x4 accS[4];
#pragma unroll
    for (int nb = 0; nb < 4; ++nb)
      for (int z = 0; z < 4; ++z) accS[nb][z] = 0.f;
    bf16x8 af[2];
#pragma unroll
    for (int kc = 0; kc < 2; ++kc)
      af[kc] = *(const bf16x8*)&Qs[wid * 16 + l15][kc * 32 + quad * 8];
#pragma unroll
    for (int nb = 0; nb < 4; ++nb) {
#pragma unroll
      for (int kc = 0; kc < 2; ++kc) {
        bf16x8 bfr = *(const bf16x8*)&Ks[nb * 16 + l15][kc * 32 + quad * 8];
        accS[nb] = __builtin_amdgcn_mfma_f32_16x16x32_bf16(af[kc], bfr, accS[nb], 0, 0, 0);
      }
    }

    // bias + online softmax
    const int ibase = i0 + wid * 16 + quad * 4;
    float pxr[4], pyr[4];
#pragma unroll
    for (int r = 0; r < 4; ++r) {
      pxr[r] = pix[wid * 16 + quad * 4 + r];
      pyr[r] = piy[wid * 16 + quad * 4 + r];
    }
    float sv[4][4];
    float rowmax[4] = {-1e30f, -1e30f, -1e30f, -1e30f};
#pragma unroll
    for (int nb = 0; nb < 4; ++nb) {
      int jcol = nb * 16 + l15;
      int j = j0 + jcol;
      float qx = pjx[jcol], qy = pjy[jcol];
      bool jsp = (j < Ls);
#pragma unroll
      for (int r = 0; r < 4; ++r) {
        int i = ibase + r;
        float s = accS[nb][r] * scale;
        float dx = pxr[r] - qx, dy = pyr[r] - qy;
        float bias = (jsp && (i < Ls)) ? -(dx * dx + dy * dy) * inv2s2 : gb;
        s += bias;
        sv[nb][r] = s;
        rowmax[r] = fmaxf(rowmax[r], s);
      }
    }
#pragma unroll
    for (int r = 0; r < 4; ++r) {
      float v = rowmax[r];
      v = fmaxf(v, __shfl_xor(v, 1));
      v = fmaxf(v, __shfl_xor(v, 2));
      v = fmaxf(v, __shfl_xor(v, 4));
      v = fmaxf(v, __shfl_xor(v, 8));
      rowmax[r] = v;
    }
    float alpha[4], rsum[4];
#pragma unroll
    for (int r = 0; r < 4; ++r) {
      float mnew = fmaxf(mrow[r], rowmax[r]);
      alpha[r] = __expf(mrow[r] - mnew);
      mrow[r] = mnew;
      rsum[r] = 0.f;
    }
#pragma unroll
    for (int nb = 0; nb < 4; ++nb) {
#pragma unroll
      for (int r = 0; r < 4; ++r) {
        float p = __expf(sv[nb][r] - mrow[r]);
        rsum[r] += p;
        Ps[wid * 16 + quad * 4 + r][nb * 16 + l15] = f2bf(p);
      }
    }
#pragma unroll
    for (int r = 0; r < 4; ++r) {
      float v = rsum[r];
      v += __shfl_xor(v, 1);
      v += __shfl_xor(v, 2);
      v += __shfl_xor(v, 4);
      v += __shfl_xor(v, 8);
      lrow[r] = lrow[r] * alpha[r] + v;
    }
#pragma unroll
    for (int nb = 0; nb < 4; ++nb)
#pragma unroll
      for (int r = 0; r < 4; ++r) accO[nb][r] *= alpha[r];

    // O += P V   (A-frag from Ps, B-frag from Vt)
#pragma unroll
    for (int kc = 0; kc < 2; ++kc) {
      bf16x8 pf = *(const bf16x8*)&Ps[wid * 16 + l15][kc * 32 + quad * 8];
#pragma unroll
      for (int nb = 0; nb < 4; ++nb) {
        bf16x8 vf = *(const bf16x8*)&Vt[nb * 16 + l15][kc * 32 + quad * 8];
        accO[nb] = __builtin_amdgcn_mfma_f32_16x16x32_bf16(pf, vf, accO[nb], 0, 0, 0);
      }
    }
  }

  // epilogue: O /= l, write f32 to [B, L, H*DH]
  float invl[4];
#pragma unroll
  for (int r = 0; r < 4; ++r) invl[r] = 1.0f / lrow[r];
#pragma unroll
  for (int nb = 0; nb < 4; ++nb) {
#pragma unroll
    for (int r = 0; r < 4; ++r) {
      int i = i0 + wid * 16 + quad * 4 + r;
      int dh = nb * 16 + l15;
      attn_out[((size_t)b * NL + i) * (NH * DH) + h * DH + dh] = accO[nb][r] * invl[r];
    }
  }
}

// ---------------------------------------------------------------------------
extern "C" void kernel_launch(void* const* d_in, const int* in_sizes, int n_in,
                              void* d_out, int out_size, void* d_ws, size_t ws_size,
                              hipStream_t stream) {
  const float* x         = (const float*)d_in[0];
  const float* positions = (const float*)d_in[1];
  const float* w_qkv     = (const float*)d_in[2];
  const float* w_out     = (const float*)d_in[3];
  const float* b_out     = (const float*)d_in[4];
  const float* log_sigma = (const float*)d_in[5];
  const float* gbias     = (const float*)d_in[6];
  const int*   ns        = (const int*)d_in[7];

  const size_t QKV_ELEMS = (size_t)NB * NH * NL * DH;  // 2,097,152
  unsigned short* qb = (unsigned short*)d_ws;
  unsigned short* kb = qb + QKV_ELEMS;
  unsigned short* vb = kb + QKV_ELEMS;
  float* attn_out = (float*)(vb + QKV_ELEMS);          // 12 MB offset, f32 [B,L,512]

  // 1) QKV projection: M=4096, N=1536, K=512
  dim3 g1(NB * NL / 128, (3 * NH * DH) / 128);
  gemm_bf16_kernel<0><<<g1, 256, 0, stream>>>(x, w_qkv, nullptr, qb, kb, vb, nullptr, ND);

  // 2) flash attention
  dim3 g2(NL / 64, NH, NB);
  flash_kernel<<<g2, 256, 0, stream>>>(qb, kb, vb, positions, log_sigma, gbias, ns, attn_out);

  // 3) output projection: M=4096, N=512, K=512 (+ bias)
  dim3 g3(NB * NL / 128, ND / 128);
  gemm_bf16_kernel<1><<<g3, 256, 0, stream>>>(attn_out, w_out, b_out, nullptr, nullptr, nullptr,
                                              (float*)d_out, NH * DH);
}

// Round 2
// 210.558 us; speedup vs baseline: 1.1416x; 1.1416x over previous
//
#include <hip/hip_runtime.h>
#include <stdint.h>
#include <stddef.h>

// Problem constants (fixed by setup_inputs)
#define NB   2      // batch
#define NL   2048   // seq len
#define ND   512    // model dim
#define NH   8      // heads
#define DH   64     // dim head
#define LOG2E 1.44269504f

typedef __attribute__((ext_vector_type(8))) short bf16x8;
typedef __attribute__((ext_vector_type(4))) float f32x4;

__device__ __forceinline__ unsigned short f2bf(float f) {
  union { float f; unsigned int u; } c; c.f = f;
  unsigned int u = c.u;
  unsigned int r = u + 0x7fffu + ((u >> 16) & 1u);
  return (unsigned short)(r >> 16);
}

__device__ __forceinline__ float fexp2(float x) {
#if __has_builtin(__builtin_amdgcn_exp2f)
  return __builtin_amdgcn_exp2f(x);
#else
  return exp2f(x);
#endif
}

// async global->LDS 16B copy; lanes of a wave must target base + lane*16
__device__ __forceinline__ void gl_lds16(const unsigned short* g, unsigned short* l) {
#if __has_builtin(__builtin_amdgcn_global_load_lds)
  __builtin_amdgcn_global_load_lds(
      (const __attribute__((address_space(1))) unsigned int*)g,
      (__attribute__((address_space(3))) unsigned int*)l, 16, 0, 0);
#else
  *(uint4*)l = *(const uint4*)g;
#endif
}

// ---------------------------------------------------------------------------
// f32 -> bf16 conversion for x, w_qkv, w_out (one flat grid over float4 chunks)
// ---------------------------------------------------------------------------
#define XC  524288   // 4096*512/4
#define WQC 196608   // 1536*512/4
#define WOC 65536    // 512*512/4
__global__ void cvt_f32_bf16(const float* __restrict__ x, const float* __restrict__ wq,
                             const float* __restrict__ wo, unsigned short* __restrict__ xb,
                             unsigned short* __restrict__ wqb, unsigned short* __restrict__ wob) {
  int idx = blockIdx.x * 256 + threadIdx.x;
  const float* src; unsigned short* dst; int off;
  if (idx < XC)            { src = x;  dst = xb;  off = idx; }
  else if (idx < XC + WQC) { src = wq; dst = wqb; off = idx - XC; }
  else                     { src = wo; dst = wob; off = idx - XC - WQC; }
  float4 f = ((const float4*)src)[off];
  ushort4 o;
  o.x = f2bf(f.x); o.y = f2bf(f.y); o.z = f2bf(f.z); o.w = f2bf(f.w);
  ((ushort4*)dst)[off] = o;
}

// ---------------------------------------------------------------------------
// bf16 128x128-tile MFMA GEMM (m97 structure): C[m][n] = sum_k A[m][k]*B[n][k]
// MODE 0: QKV epilogue -> q (pre-scaled by 0.125*log2e) [b,h,l,dh], k [b,h,l,dh],
//         v TRANSPOSED [b,h,dh,l], all bf16.
// MODE 1: f32 out + bias, [M x 512] row-major.
// ---------------------------------------------------------------------------
template<int MODE>
__global__ __launch_bounds__(256, 2) void gemm_bf16(
    const unsigned short* __restrict__ A, const unsigned short* __restrict__ Bm,
    const float* __restrict__ bias,
    unsigned short* __restrict__ qo, unsigned short* __restrict__ ko,
    unsigned short* __restrict__ vTo, float* __restrict__ out, int K)
{
  __shared__ __align__(16) unsigned short As[128 * 32];
  __shared__ __align__(16) unsigned short Bs[128 * 32];
  const int tid = threadIdx.x, wid = tid >> 6, lane = tid & 63;
  const int quad = lane >> 4, l15 = lane & 15;
  const int m0 = blockIdx.x * 128, n0 = blockIdx.y * 128;
  const int wm = (wid >> 1) * 64, wn = (wid & 1) * 64;

  f32x4 acc[4][4];
#pragma unroll
  for (int a = 0; a < 4; ++a)
#pragma unroll
    for (int b = 0; b < 4; ++b)
#pragma unroll
      for (int z = 0; z < 4; ++z) acc[a][b][z] = 0.f;

  for (int k0 = 0; k0 < K; k0 += 32) {
#pragma unroll
    for (int p = 0; p < 2; ++p) {
      int c = p * 256 + wid * 64 + lane;   // lane-linear within wave
      int row = c >> 2, off = c & 3;
      gl_lds16(A  + (size_t)(m0 + row) * K + k0 + off * 8, &As[c * 8]);
      gl_lds16(Bm + (size_t)(n0 + row) * K + k0 + off * 8, &Bs[c * 8]);
    }
    __syncthreads();   // drains vmcnt then barriers
    bf16x8 af[4], bfr[4];
#pragma unroll
    for (int mb = 0; mb < 4; ++mb)
      af[mb] = *(const bf16x8*)&As[(wm + mb * 16 + l15) * 32 + quad * 8];
#pragma unroll
    for (int nb = 0; nb < 4; ++nb)
      bfr[nb] = *(const bf16x8*)&Bs[(wn + nb * 16 + l15) * 32 + quad * 8];
#pragma unroll
    for (int mb = 0; mb < 4; ++mb)
#pragma unroll
      for (int nb = 0; nb < 4; ++nb)
        acc[mb][nb] = __builtin_amdgcn_mfma_f32_16x16x32_bf16(af[mb], bfr[nb], acc[mb][nb], 0, 0, 0);
    __syncthreads();
  }

  const float QSCALE = 0.125f * LOG2E;
#pragma unroll
  for (int mb = 0; mb < 4; ++mb) {
#pragma unroll
    for (int r = 0; r < 4; ++r) {
      int m  = m0 + wm + mb * 16 + quad * 4 + r;
      int bb = m >> 11;
      int ll = m & 2047;
#pragma unroll
      for (int nb = 0; nb < 4; ++nb) {
        int n = n0 + wn + nb * 16 + l15;
        float v = acc[mb][nb][r];
        if (MODE == 0) {
          int s  = n >> 9;
          int hh = (n >> 6) & 7;
          int dh = n & 63;
          if (s == 0)      qo[(((size_t)bb * NH + hh) * NL + ll) * DH + dh] = f2bf(v * QSCALE);
          else if (s == 1) ko[(((size_t)bb * NH + hh) * NL + ll) * DH + dh] = f2bf(v);
          else             vTo[(((size_t)bb * NH + hh) * DH + dh) * NL + ll] = f2bf(v);
        } else {
          out[(size_t)m * ND + n] = v + bias[n];
        }
      }
    }
  }
}

// ---------------------------------------------------------------------------
// Flash attention, fixed-shift softmax (no running max — exact after row
// normalization since the -8 shift and global_bias are row constants).
// Block = 128 threads (2 waves). q-tile = 64 rows; wave owns 32 rows (2
// m-blocks). j-tiles of 64, register-prefetched across the barrier.
// q is pre-scaled by 0.125*log2e, so MFMA S is already in log2 domain.
// Output: bf16 [B, L, H*DH].
// ---------------------------------------------------------------------------
__global__ __launch_bounds__(128) void flash_kernel(
    const unsigned short* __restrict__ qb, const unsigned short* __restrict__ kb,
    const unsigned short* __restrict__ vTb, const float* __restrict__ positions,
    const float* __restrict__ log_sigma, const float* __restrict__ gbias_p,
    const int* __restrict__ ns_p, unsigned short* __restrict__ attnb)
{
  const int it = blockIdx.x;      // 0..31
  const int h  = blockIdx.y;
  const int b  = blockIdx.z;
  const int i0 = it * 64;
  const int Ls = ns_p[0];
  const float gb = gbias_p[0];
  const float sig = __expf(log_sigma[h]);
  const float inv2s2 = 0.5f / (sig * sig);
  const float CI = LOG2E * inv2s2;          // c*inv2s2
  const float A2 = 2.0f * CI;               // cross-term coeff
  const float CG = LOG2E * gb * 0.5f;       // half of c*gb
  const float C8N = -8.0f * LOG2E;          // fixed shift

  const int tid  = threadIdx.x;
  const int wid  = tid >> 6;      // 0..1
  const int lane = tid & 63;
  const int quad = lane >> 4;
  const int l15  = lane & 15;

  __shared__ __align__(16) unsigned short Ks[64][72];
  __shared__ __align__(16) unsigned short Vt[64][72];   // [dh][j]
  __shared__ __align__(16) unsigned short Ps[64][72];
  __shared__ __align__(16) float4 pjc[64];              // {pjx2, pjy2, rjCm, 0}

  const size_t bh = (size_t)b * NH + h;
  const unsigned short* qbase  = qb  + (bh * NL + i0) * DH;
  const unsigned short* kbase  = kb  + bh * NL * DH;
  const unsigned short* vtbase = vTb + bh * DH * NL;

  // hoisted Q fragments (wave rows wid*32 + mb*16 + l15)
  bf16x8 af[2][2];
#pragma unroll
  for (int mb = 0; mb < 2; ++mb)
#pragma unroll
    for (int kc = 0; kc < 2; ++kc)
      af[mb][kc] = *(const bf16x8*)(qbase + (size_t)(wid * 32 + mb * 16 + l15) * DH + kc * 32 + quad * 8);

  // i-side per-row constants (rows wid*32 + mb*16 + quad*4 + r)
  float pix_[2][4], piy_[2][4], riCm[2][4], ispf[2][4];
#pragma unroll
  for (int mb = 0; mb < 2; ++mb)
#pragma unroll
    for (int r = 0; r < 4; ++r) {
      int ig = i0 + wid * 32 + mb * 16 + quad * 4 + r;
      float px = 0.f, py = 0.f, sf = 0.f, rc = 0.f;
      if (ig < Ls) {
        float2 p2 = *(const float2*)(positions + ((size_t)b * Ls + ig) * 2);
        px = p2.x; py = p2.y; sf = 1.f;
        rc = -(CI * (px * px + py * py)) - CG;
      }
      pix_[mb][r] = px; piy_[mb][r] = py; ispf[mb][r] = sf; riCm[mb][r] = rc;
    }

  f32x4 accO[2][4];
  float rsum[2][4];
#pragma unroll
  for (int mb = 0; mb < 2; ++mb) {
#pragma unroll
    for (int nb = 0; nb < 4; ++nb)
#pragma unroll
      for (int z = 0; z < 4; ++z) accO[mb][nb][z] = 0.f;
#pragma unroll
    for (int r = 0; r < 4; ++r) rsum[mb][r] = 0.f;
  }

  // ---- register prefetch of tile 0 ----
  uint4 kr[4], vr[4];
  float2 pr = make_float2(0.f, 0.f);
  {
#pragma unroll
    for (int p = 0; p < 4; ++p) {
      int c = p * 128 + tid;
      int row = c >> 3, off = c & 7;
      kr[p] = *(const uint4*)(kbase  + (size_t)row * DH + off * 8);
      vr[p] = *(const uint4*)(vtbase + (size_t)row * NL + off * 8);
    }
    if (tid < 64 && tid < Ls)
      pr = *(const float2*)(positions + ((size_t)b * Ls + tid) * 2);
  }

  for (int jt = 0; jt < NL / 64; ++jt) {
    const int j0 = jt * 64;
    __syncthreads();   // previous compute done reading LDS (and drains prefetch vmcnt)

    // regs -> LDS
#pragma unroll
    for (int p = 0; p < 4; ++p) {
      int c = p * 128 + tid;
      int row = c >> 3, off = c & 7;
      *(uint4*)&Ks[row][off * 8] = kr[p];
      *(uint4*)&Vt[row][off * 8] = vr[p];
    }
    if (tid < 64) {
      bool jsp = (j0 + tid) < Ls;
      float px = jsp ? pr.x : 0.f, py = jsp ? pr.y : 0.f;
      float rc = jsp ? (-(CI * (px * px + py * py)) - CG) : 0.f;
      pjc[tid] = make_float4(A2 * px, A2 * py, rc, 0.f);
    }
    __syncthreads();

    // issue prefetch for next tile (waited at next loop-top barrier)
    if (jt + 1 < NL / 64) {
      const int jn = (jt + 1) * 64;
#pragma unroll
      for (int p = 0; p < 4; ++p) {
        int c = p * 128 + tid;
        int row = c >> 3, off = c & 7;
        kr[p] = *(const uint4*)(kbase  + (size_t)(jn + row) * DH + off * 8);
        vr[p] = *(const uint4*)(vtbase + (size_t)row * NL + jn + off * 8);
      }
      if (tid < 64 && (jn + tid) < Ls)
        pr = *(const float2*)(positions + ((size_t)b * Ls + jn + tid) * 2);
    }

    // ---- S = Q' K^T (already includes 0.125*log2e scale via q) ----
    f32x4 accS[2][4];
#pragma unroll
    for (int mb = 0; mb < 2; ++mb)
#pragma unroll
      for (int nb = 0; nb < 4; ++nb)
#pragma unroll
        for (int z = 0; z < 4; ++z) accS[mb][nb][z] = 0.f;
#pragma unroll
    for (int nb = 0; nb < 4; ++nb) {
      bf16x8 b0 = *(const bf16x8*)&Ks[nb * 16 + l15][quad * 8];
      bf16x8 b1 = *(const bf16x8*)&Ks[nb * 16 + l15][32 + quad * 8];
#pragma unroll
      for (int mb = 0; mb < 2; ++mb) {
        accS[mb][nb] = __builtin_amdgcn_mfma_f32_16x16x32_bf16(af[mb][0], b0, accS[mb][nb], 0, 0, 0);
        accS[mb][nb] = __builtin_amdgcn_mfma_f32_16x16x32_bf16(af[mb][1], b1, accS[mb][nb], 0, 0, 0);
      }
    }

    // ---- bias + exp2 + P store ----
    float4 pc[4]; float jspf_[4];
#pragma unroll
    for (int nb = 0; nb < 4; ++nb) {
      pc[nb] = pjc[nb * 16 + l15];
      jspf_[nb] = ((j0 + nb * 16 + l15) < Ls) ? 1.f : 0.f;
    }
#pragma unroll
    for (int mb = 0; mb < 2; ++mb)
#pragma unroll
      for (int nb = 0; nb < 4; ++nb)
#pragma unroll
        for (int r = 0; r < 4; ++r) {
          float t = accS[mb][nb][r] + C8N;
          t = __builtin_fmaf(ispf[mb][r], pc[nb].z, t);   // ispf * rjCm
          t = __builtin_fmaf(jspf_[nb], riCm[mb][r], t);  // jspf * riCm
          t = __builtin_fmaf(piy_[mb][r], pc[nb].y, t);   // cross y
          t = __builtin_fmaf(pix_[mb][r], pc[nb].x, t);   // cross x
          float p = fexp2(t);
          rsum[mb][r] += p;
          Ps[wid * 32 + mb * 16 + quad * 4 + r][nb * 16 + l15] = f2bf(p);
        }

    // ---- O += P V (Ps is wave-private: no barrier needed) ----
    bf16x8 pf[2][2];
#pragma unroll
    for (int mb = 0; mb < 2; ++mb) {
      pf[mb][0] = *(const bf16x8*)&Ps[wid * 32 + mb * 16 + l15][quad * 8];
      pf[mb][1] = *(const bf16x8*)&Ps[wid * 32 + mb * 16 + l15][32 + quad * 8];
    }
#pragma unroll
    for (int nb = 0; nb < 4; ++nb) {
      bf16x8 v0 = *(const bf16x8*)&Vt[nb * 16 + l15][quad * 8];
      bf16x8 v1 = *(const bf16x8*)&Vt[nb * 16 + l15][32 + quad * 8];
#pragma unroll
      for (int mb = 0; mb < 2; ++mb) {
        accO[mb][nb] = __builtin_amdgcn_mfma_f32_16x16x32_bf16(pf[mb][0], v0, accO[mb][nb], 0, 0, 0);
        accO[mb][nb] = __builtin_amdgcn_mfma_f32_16x16x32_bf16(pf[mb][1], v1, accO[mb][nb], 0, 0, 0);
      }
    }
  }

  // ---- epilogue: reduce row sums over the 16 lanes of each quad-group ----
#pragma unroll
  for (int mb = 0; mb < 2; ++mb)
#pragma unroll
    for (int r = 0; r < 4; ++r) {
      float v = rsum[mb][r];
      v += __shfl_xor(v, 1);
      v += __shfl_xor(v, 2);
      v += __shfl_xor(v, 4);
      v += __shfl_xor(v, 8);
      rsum[mb][r] = 1.0f / v;
    }
#pragma unroll
  for (int mb = 0; mb < 2; ++mb)
#pragma unroll
    for (int nb = 0; nb < 4; ++nb)
#pragma unroll
      for (int r = 0; r < 4; ++r) {
        int ig = i0 + wid * 32 + mb * 16 + quad * 4 + r;
        attnb[((size_t)b * NL + ig) * ND + h * DH + nb * 16 + l15] =
            f2bf(accO[mb][nb][r] * rsum[mb][r]);
      }
}

// ---------------------------------------------------------------------------
extern "C" void kernel_launch(void* const* d_in, const int* in_sizes, int n_in,
                              void* d_out, int out_size, void* d_ws, size_t ws_size,
                              hipStream_t stream) {
  const float* x         = (const float*)d_in[0];
  const float* positions = (const float*)d_in[1];
  const float* w_qkv     = (const float*)d_in[2];
  const float* w_out     = (const float*)d_in[3];
  const float* b_out     = (const float*)d_in[4];
  const float* log_sigma = (const float*)d_in[5];
  const float* gbias     = (const float*)d_in[6];
  const int*   ns        = (const int*)d_in[7];

  // workspace layout (shorts): xb (reused as attn bf16) | wqb | wob | q | k | vT
  unsigned short* ws = (unsigned short*)d_ws;
  unsigned short* xb  = ws;                    // 2,097,152 (also attn output)
  unsigned short* wqb = xb  + 2097152;         //   786,432
  unsigned short* wob = wqb + 786432;          //   262,144
  unsigned short* qbf = wob + 262144;          // 2,097,152
  unsigned short* kbf = qbf + 2097152;         // 2,097,152
  unsigned short* vTf = kbf + 2097152;         // 2,097,152  (total ~18.9 MB)

  // 1) f32 -> bf16 conversions
  cvt_f32_bf16<<<(XC + WQC + WOC) / 256, 256, 0, stream>>>(x, w_qkv, w_out, xb, wqb, wob);

  // 2) QKV projection: M=4096, N=1536, K=512 -> q(scaled), k, v^T
  dim3 g1(NB * NL / 128, (3 * NH * DH) / 128);
  gemm_bf16<0><<<g1, 256, 0, stream>>>(xb, wqb, nullptr, qbf, kbf, vTf, nullptr, ND);

  // 3) flash attention -> attn bf16 (into xb region; x no longer needed)
  dim3 g2(NL / 64, NH, NB);
  flash_kernel<<<g2, 128, 0, stream>>>(qbf, kbf, vTf, positions, log_sigma, gbias, ns, xb);

  // 4) output projection: M=4096, N=512, K=512 (+bias) -> f32 d_out
  dim3 g3(NB * NL / 128, ND / 128);
  gemm_bf16<1><<<g3, 256, 0, stream>>>(xb, wob, b_out, nullptr, nullptr, nullptr,
                                       (float*)d_out, NH * DH);
}

// Round 3
// 167.123 us; speedup vs baseline: 1.4383x; 1.2599x over previous
//
#include <hip/hip_runtime.h>
#include <stdint.h>
#include <stddef.h>

// Problem constants (fixed by setup_inputs)
#define NB   2      // batch
#define NL   2048   // seq len
#define ND   512    // model dim
#define NH   8      // heads
#define DH   64     // dim head
#define LOG2E 1.44269504f
#define NIT  16     // i-tiles (128 rows each)
#define RG_TOT 32768  // NB*NH*NIT*128 rows of partials

typedef __attribute__((ext_vector_type(8))) short bf16x8;
typedef __attribute__((ext_vector_type(4))) float f32x4;

__device__ __forceinline__ unsigned short f2bf(float f) {
  union { float f; unsigned int u; } c; c.f = f;
  unsigned int u = c.u;
  unsigned int r = u + 0x7fffu + ((u >> 16) & 1u);
  return (unsigned short)(r >> 16);
}

__device__ __forceinline__ float fexp2(float x) {
#if __has_builtin(__builtin_amdgcn_exp2f)
  return __builtin_amdgcn_exp2f(x);
#else
  return exp2f(x);
#endif
}

// async global->LDS 16B copy; lanes of a wave must target base + lane*16
__device__ __forceinline__ void gl_lds16(const unsigned short* g, unsigned short* l) {
#if __has_builtin(__builtin_amdgcn_global_load_lds)
  __builtin_amdgcn_global_load_lds(
      (const __attribute__((address_space(1))) unsigned int*)g,
      (__attribute__((address_space(3))) unsigned int*)l, 16, 0, 0);
#else
  *(uint4*)l = *(const uint4*)g;
#endif
}

// ---------------------------------------------------------------------------
// f32 -> bf16 conversion for x, w_qkv, w_out (one flat grid over float4 chunks)
// ---------------------------------------------------------------------------
#define XC  524288   // 4096*512/4
#define WQC 196608   // 1536*512/4
#define WOC 65536    // 512*512/4
__global__ void cvt_f32_bf16(const float* __restrict__ x, const float* __restrict__ wq,
                             const float* __restrict__ wo, unsigned short* __restrict__ xb,
                             unsigned short* __restrict__ wqb, unsigned short* __restrict__ wob) {
  int idx = blockIdx.x * 256 + threadIdx.x;
  const float* src; unsigned short* dst; int off;
  if (idx < XC)            { src = x;  dst = xb;  off = idx; }
  else if (idx < XC + WQC) { src = wq; dst = wqb; off = idx - XC; }
  else                     { src = wo; dst = wob; off = idx - XC - WQC; }
  float4 f = ((const float4*)src)[off];
  ushort4 o;
  o.x = f2bf(f.x); o.y = f2bf(f.y); o.z = f2bf(f.z); o.w = f2bf(f.w);
  ((ushort4*)dst)[off] = o;
}

// ---------------------------------------------------------------------------
// bf16 128x128-tile MFMA GEMM: C[m][n] = sum_k A[m][k]*B[n][k]
// MODE 0: QKV epilogue -> q (pre-scaled by 0.125*log2e), k, v, ALL row-major
//         [b,h,l,dh] bf16 (fully coalesced; V transposed by separate kernel).
// MODE 1: f32 out + bias, [M x 512] row-major.
// ---------------------------------------------------------------------------
template<int MODE>
__global__ __launch_bounds__(256, 2) void gemm_bf16(
    const unsigned short* __restrict__ A, const unsigned short* __restrict__ Bm,
    const float* __restrict__ bias,
    unsigned short* __restrict__ qo, unsigned short* __restrict__ ko,
    unsigned short* __restrict__ vo, float* __restrict__ out, int K)
{
  __shared__ __align__(16) unsigned short As[128 * 32];
  __shared__ __align__(16) unsigned short Bs[128 * 32];
  const int tid = threadIdx.x, wid = tid >> 6, lane = tid & 63;
  const int quad = lane >> 4, l15 = lane & 15;
  const int m0 = blockIdx.x * 128, n0 = blockIdx.y * 128;
  const int wm = (wid >> 1) * 64, wn = (wid & 1) * 64;

  f32x4 acc[4][4];
#pragma unroll
  for (int a = 0; a < 4; ++a)
#pragma unroll
    for (int b = 0; b < 4; ++b)
#pragma unroll
      for (int z = 0; z < 4; ++z) acc[a][b][z] = 0.f;

  for (int k0 = 0; k0 < K; k0 += 32) {
#pragma unroll
    for (int p = 0; p < 2; ++p) {
      int c = p * 256 + wid * 64 + lane;   // lane-linear within wave
      int row = c >> 2, off = c & 3;
      gl_lds16(A  + (size_t)(m0 + row) * K + k0 + off * 8, &As[c * 8]);
      gl_lds16(Bm + (size_t)(n0 + row) * K + k0 + off * 8, &Bs[c * 8]);
    }
    __syncthreads();
    bf16x8 af[4], bfr[4];
#pragma unroll
    for (int mb = 0; mb < 4; ++mb)
      af[mb] = *(const bf16x8*)&As[(wm + mb * 16 + l15) * 32 + quad * 8];
#pragma unroll
    for (int nb = 0; nb < 4; ++nb)
      bfr[nb] = *(const bf16x8*)&Bs[(wn + nb * 16 + l15) * 32 + quad * 8];
#pragma unroll
    for (int mb = 0; mb < 4; ++mb)
#pragma unroll
      for (int nb = 0; nb < 4; ++nb)
        acc[mb][nb] = __builtin_amdgcn_mfma_f32_16x16x32_bf16(af[mb], bfr[nb], acc[mb][nb], 0, 0, 0);
    __syncthreads();
  }

  const float QSCALE = 0.125f * LOG2E;
#pragma unroll
  for (int mb = 0; mb < 4; ++mb) {
#pragma unroll
    for (int r = 0; r < 4; ++r) {
      int m  = m0 + wm + mb * 16 + quad * 4 + r;
      int bb = m >> 11;
      int ll = m & 2047;
#pragma unroll
      for (int nb = 0; nb < 4; ++nb) {
        int n = n0 + wn + nb * 16 + l15;
        float v = acc[mb][nb][r];
        if (MODE == 0) {
          int s  = n >> 9;            // lane-uniform
          int hh = (n >> 6) & 7;
          int dh = n & 63;
          size_t base = (((size_t)bb * NH + hh) * NL + ll) * DH + dh;
          if (s == 0)      qo[base] = f2bf(v * QSCALE);
          else if (s == 1) ko[base] = f2bf(v);
          else             vo[base] = f2bf(v);
        } else {
          out[(size_t)m * ND + n] = v + bias[n];
        }
      }
    }
  }
}

// ---------------------------------------------------------------------------
// V transpose: [b,h,l,dh] -> [b,h,dh,l], LDS-tiled, coalesced both sides.
// grid (NL/64, NB*NH), 256 threads.
// ---------------------------------------------------------------------------
__global__ __launch_bounds__(256) void transpose_v(const unsigned short* __restrict__ v,
                                                   unsigned short* __restrict__ vT) {
  __shared__ unsigned short T[64][74];   // 74: lseg-groups land 8 banks apart
  const int l0 = blockIdx.x * 64;
  const int bh = blockIdx.y;
  const unsigned short* src = v + ((size_t)bh * NL + l0) * DH;
  unsigned short* dst = vT + (size_t)bh * DH * NL;
#pragma unroll
  for (int p = 0; p < 2; ++p) {
    int c = p * 256 + threadIdx.x;
    int row = c >> 3, seg = c & 7;
    *(uint4*)&T[row][seg * 8] = *(const uint4*)(src + row * DH + seg * 8);
  }
  __syncthreads();
#pragma unroll
  for (int p = 0; p < 2; ++p) {
    int c = p * 256 + threadIdx.x;
    int drow = c >> 3, lseg = c & 7;
    unsigned short u[8];
#pragma unroll
    for (int z = 0; z < 8; ++z) u[z] = T[lseg * 8 + z][drow];
    *(uint4*)(dst + (size_t)drow * NL + l0 + lseg * 8) = *(uint4*)u;
  }
}

// ---------------------------------------------------------------------------
// Flash attention, fixed-shift softmax, split-j partials.
// Block = 256 threads (4 waves); 128 q-rows/block (32 rows/wave, 2 m-blocks).
// gridDim.x = NIT*2: it = x>>1, js = x&1 (j-half). 16 j-tiles of 64 per block.
// Writes UNNORMALIZED accO (f32) + row sums to partial buffers; combine
// kernel merges the two halves (fixed shift => partials add linearly).
// q pre-scaled by 0.125*log2e => S already in log2 domain.
// ---------------------------------------------------------------------------
__global__ __launch_bounds__(256, 2) void flash_kernel(
    const unsigned short* __restrict__ qb, const unsigned short* __restrict__ kb,
    const unsigned short* __restrict__ vTb, const float* __restrict__ positions,
    const float* __restrict__ log_sigma, const float* __restrict__ gbias_p,
    const int* __restrict__ ns_p, float* __restrict__ Pbuf, float* __restrict__ rsbuf)
{
  const int it = blockIdx.x >> 1;
  const int js = blockIdx.x & 1;
  const int h  = blockIdx.y;
  const int b  = blockIdx.z;
  const int i0 = it * 128;
  const int jbase = js * (NL / 2);
  const int Ls = ns_p[0];
  const float gb = gbias_p[0];
  const float sig = __expf(log_sigma[h]);
  const float inv2s2 = 0.5f / (sig * sig);
  const float CI = LOG2E * inv2s2;
  const float A2 = 2.0f * CI;
  const float CG = LOG2E * gb * 0.5f;
  const float C8N = -8.0f * LOG2E;

  const int tid  = threadIdx.x;
  const int wid  = tid >> 6;      // 0..3
  const int lane = tid & 63;
  const int quad = lane >> 4;
  const int l15  = lane & 15;

  __shared__ __align__(16) unsigned short Ks[64][72];
  __shared__ __align__(16) unsigned short Vt[64][72];   // [dh][j]
  __shared__ __align__(16) unsigned short Ps[128][72];
  __shared__ __align__(16) float4 pjc[64];              // {A2*pjx, A2*pjy, rjCm, 0}

  const size_t bh = (size_t)b * NH + h;
  const unsigned short* qbase  = qb  + (bh * NL + i0) * DH;
  const unsigned short* kbase  = kb  + bh * NL * DH;
  const unsigned short* vtbase = vTb + bh * DH * NL;

  // hoisted Q fragments: rows wid*32 + mb*16 + l15
  bf16x8 af[2][2];
#pragma unroll
  for (int mb = 0; mb < 2; ++mb)
#pragma unroll
    for (int kc = 0; kc < 2; ++kc)
      af[mb][kc] = *(const bf16x8*)(qbase + (size_t)(wid * 32 + mb * 16 + l15) * DH + kc * 32 + quad * 8);

  // i-side per-row constants
  float pix_[2][4], piy_[2][4], riCm[2][4], ispf[2][4];
#pragma unroll
  for (int mb = 0; mb < 2; ++mb)
#pragma unroll
    for (int r = 0; r < 4; ++r) {
      int ig = i0 + wid * 32 + mb * 16 + quad * 4 + r;
      float px = 0.f, py = 0.f, sf = 0.f, rc = 0.f;
      if (ig < Ls) {
        float2 p2 = *(const float2*)(positions + ((size_t)b * Ls + ig) * 2);
        px = p2.x; py = p2.y; sf = 1.f;
        rc = -(CI * (px * px + py * py)) - CG;
      }
      pix_[mb][r] = px; piy_[mb][r] = py; ispf[mb][r] = sf; riCm[mb][r] = rc;
    }

  f32x4 accO[2][4];
  float rsum[2][4];
#pragma unroll
  for (int mb = 0; mb < 2; ++mb) {
#pragma unroll
    for (int nb = 0; nb < 4; ++nb)
#pragma unroll
      for (int z = 0; z < 4; ++z) accO[mb][nb][z] = 0.f;
#pragma unroll
    for (int r = 0; r < 4; ++r) rsum[mb][r] = 0.f;
  }

  // ---- register prefetch of tile 0 ----
  uint4 kr[2], vr[2];
  float2 pr = make_float2(0.f, 0.f);
  {
#pragma unroll
    for (int p = 0; p < 2; ++p) {
      int c = p * 256 + tid;          // 512 chunks: 64 rows x 8 segs
      int row = c >> 3, off = c & 7;
      kr[p] = *(const uint4*)(kbase  + (size_t)(jbase + row) * DH + off * 8);
      vr[p] = *(const uint4*)(vtbase + (size_t)row * NL + jbase + off * 8);
    }
    if (tid < 64 && (jbase + tid) < Ls)
      pr = *(const float2*)(positions + ((size_t)b * Ls + jbase + tid) * 2);
  }

  for (int jt = 0; jt < 16; ++jt) {
    const int j0 = jbase + jt * 64;
    __syncthreads();

    // regs -> LDS
#pragma unroll
    for (int p = 0; p < 2; ++p) {
      int c = p * 256 + tid;
      int row = c >> 3, off = c & 7;
      *(uint4*)&Ks[row][off * 8] = kr[p];
      *(uint4*)&Vt[row][off * 8] = vr[p];
    }
    if (tid < 64) {
      bool jsp = (j0 + tid) < Ls;
      float px = jsp ? pr.x : 0.f, py = jsp ? pr.y : 0.f;
      float rc = jsp ? (-(CI * (px * px + py * py)) - CG) : 0.f;
      pjc[tid] = make_float4(A2 * px, A2 * py, rc, 0.f);
    }
    __syncthreads();

    // prefetch next tile
    if (jt + 1 < 16) {
      const int jn = jbase + (jt + 1) * 64;
#pragma unroll
      for (int p = 0; p < 2; ++p) {
        int c = p * 256 + tid;
        int row = c >> 3, off = c & 7;
        kr[p] = *(const uint4*)(kbase  + (size_t)(jn + row) * DH + off * 8);
        vr[p] = *(const uint4*)(vtbase + (size_t)row * NL + jn + off * 8);
      }
      if (tid < 64 && (jn + tid) < Ls)
        pr = *(const float2*)(positions + ((size_t)b * Ls + jn + tid) * 2);
    }

    // ---- S = Q' K^T ----
    f32x4 accS[2][4];
#pragma unroll
    for (int mb = 0; mb < 2; ++mb)
#pragma unroll
      for (int nb = 0; nb < 4; ++nb)
#pragma unroll
        for (int z = 0; z < 4; ++z) accS[mb][nb][z] = 0.f;
#pragma unroll
    for (int nb = 0; nb < 4; ++nb) {
      bf16x8 b0 = *(const bf16x8*)&Ks[nb * 16 + l15][quad * 8];
      bf16x8 b1 = *(const bf16x8*)&Ks[nb * 16 + l15][32 + quad * 8];
#pragma unroll
      for (int mb = 0; mb < 2; ++mb) {
        accS[mb][nb] = __builtin_amdgcn_mfma_f32_16x16x32_bf16(af[mb][0], b0, accS[mb][nb], 0, 0, 0);
        accS[mb][nb] = __builtin_amdgcn_mfma_f32_16x16x32_bf16(af[mb][1], b1, accS[mb][nb], 0, 0, 0);
      }
    }

    // ---- bias + exp2 + P store ----
    float4 pc[4]; float jspf_[4];
#pragma unroll
    for (int nb = 0; nb < 4; ++nb) {
      pc[nb] = pjc[nb * 16 + l15];
      jspf_[nb] = ((j0 + nb * 16 + l15) < Ls) ? 1.f : 0.f;
    }
#pragma unroll
    for (int mb = 0; mb < 2; ++mb)
#pragma unroll
      for (int nb = 0; nb < 4; ++nb)
#pragma unroll
        for (int r = 0; r < 4; ++r) {
          float t = accS[mb][nb][r] + C8N;
          t = __builtin_fmaf(ispf[mb][r], pc[nb].z, t);
          t = __builtin_fmaf(jspf_[nb], riCm[mb][r], t);
          t = __builtin_fmaf(piy_[mb][r], pc[nb].y, t);
          t = __builtin_fmaf(pix_[mb][r], pc[nb].x, t);
          float p = fexp2(t);
          rsum[mb][r] += p;
          Ps[wid * 32 + mb * 16 + quad * 4 + r][nb * 16 + l15] = f2bf(p);
        }

    // ---- O += P V (Ps rows are wave-private) ----
    bf16x8 pf[2][2];
#pragma unroll
    for (int mb = 0; mb < 2; ++mb) {
      pf[mb][0] = *(const bf16x8*)&Ps[wid * 32 + mb * 16 + l15][quad * 8];
      pf[mb][1] = *(const bf16x8*)&Ps[wid * 32 + mb * 16 + l15][32 + quad * 8];
    }
#pragma unroll
    for (int nb = 0; nb < 4; ++nb) {
      bf16x8 v0 = *(const bf16x8*)&Vt[nb * 16 + l15][quad * 8];
      bf16x8 v1 = *(const bf16x8*)&Vt[nb * 16 + l15][32 + quad * 8];
#pragma unroll
      for (int mb = 0; mb < 2; ++mb) {
        accO[mb][nb] = __builtin_amdgcn_mfma_f32_16x16x32_bf16(pf[mb][0], v0, accO[mb][nb], 0, 0, 0);
        accO[mb][nb] = __builtin_amdgcn_mfma_f32_16x16x32_bf16(pf[mb][1], v1, accO[mb][nb], 0, 0, 0);
      }
    }
  }

  // ---- epilogue: store UNNORMALIZED partials ----
#pragma unroll
  for (int mb = 0; mb < 2; ++mb)
#pragma unroll
    for (int r = 0; r < 4; ++r) {
      float v = rsum[mb][r];
      v += __shfl_xor(v, 1);
      v += __shfl_xor(v, 2);
      v += __shfl_xor(v, 4);
      v += __shfl_xor(v, 8);
      rsum[mb][r] = v;
    }
  const size_t rgbase = (bh * NIT + it) * 128;
  const size_t poff = (size_t)js * RG_TOT * DH;
#pragma unroll
  for (int mb = 0; mb < 2; ++mb)
#pragma unroll
    for (int r = 0; r < 4; ++r) {
      int row = wid * 32 + mb * 16 + quad * 4 + r;
#pragma unroll
      for (int nb = 0; nb < 4; ++nb)
        Pbuf[poff + (rgbase + row) * DH + nb * 16 + l15] = accO[mb][nb][r];
      if (l15 == 0)
        rsbuf[(size_t)js * RG_TOT + rgbase + row] = rsum[mb][r];
    }
}

// ---------------------------------------------------------------------------
// Combine split-j partials -> bf16 attn [b, l, h*64+dh]
// ---------------------------------------------------------------------------
__global__ __launch_bounds__(256) void combine_kernel(const float* __restrict__ Pbuf,
                                                      const float* __restrict__ rsbuf,
                                                      unsigned short* __restrict__ attnb) {
  int idx = blockIdx.x * 256 + threadIdx.x;       // over RG_TOT*16 float4 chunks
  int rg = idx >> 4, c4 = idx & 15;
  const float4* p4 = (const float4*)Pbuf;
  float4 p0 = p4[(size_t)rg * 16 + c4];
  float4 p1 = p4[(size_t)RG_TOT * 16 + (size_t)rg * 16 + c4];
  float rs = 1.0f / (rsbuf[rg] + rsbuf[RG_TOT + rg]);
  int bhm = rg >> 11;           // b*8+h
  int l   = rg & 2047;
  int bb  = bhm >> 3, hh = bhm & 7;
  ushort4 o;
  o.x = f2bf((p0.x + p1.x) * rs);
  o.y = f2bf((p0.y + p1.y) * rs);
  o.z = f2bf((p0.z + p1.z) * rs);
  o.w = f2bf((p0.w + p1.w) * rs);
  *(ushort4*)&attnb[(((size_t)bb * NL + l) * ND) + hh * DH + c4 * 4] = o;
}

// ---------------------------------------------------------------------------
extern "C" void kernel_launch(void* const* d_in, const int* in_sizes, int n_in,
                              void* d_out, int out_size, void* d_ws, size_t ws_size,
                              hipStream_t stream) {
  const float* x         = (const float*)d_in[0];
  const float* positions = (const float*)d_in[1];
  const float* w_qkv     = (const float*)d_in[2];
  const float* w_out     = (const float*)d_in[3];
  const float* b_out     = (const float*)d_in[4];
  const float* log_sigma = (const float*)d_in[5];
  const float* gbias     = (const float*)d_in[6];
  const int*   ns        = (const int*)d_in[7];

  // workspace layout (shorts unless noted)
  unsigned short* ws = (unsigned short*)d_ws;
  unsigned short* xb  = ws;                    // 2,097,152 (reused as attn bf16)
  unsigned short* wqb = xb  + 2097152;         //   786,432
  unsigned short* wob = wqb + 786432;          //   262,144
  unsigned short* qbf = wob + 262144;          // 2,097,152
  unsigned short* kbf = qbf + 2097152;         // 2,097,152
  unsigned short* vbf = kbf + 2097152;         // 2,097,152
  unsigned short* vTf = vbf + 2097152;         // 2,097,152
  float* Pbuf  = (float*)(vTf + 2097152);      // 2 * 32768 * 64 f32 = 16.8 MB
  float* rsbuf = Pbuf + (size_t)2 * RG_TOT * DH;  // 2 * 32768 f32

  // 1) f32 -> bf16
  cvt_f32_bf16<<<(XC + WQC + WOC) / 256, 256, 0, stream>>>(x, w_qkv, w_out, xb, wqb, wob);

  // 2) QKV projection: q(scaled), k, v row-major [b,h,l,dh]
  dim3 g1(NB * NL / 128, (3 * NH * DH) / 128);
  gemm_bf16<0><<<g1, 256, 0, stream>>>(xb, wqb, nullptr, qbf, kbf, vbf, nullptr, ND);

  // 3) V transpose -> [b,h,dh,l]
  dim3 gt(NL / 64, NB * NH);
  transpose_v<<<gt, 256, 0, stream>>>(vbf, vTf);

  // 4) flash attention partials (split-j by 2)
  dim3 g2(NIT * 2, NH, NB);
  flash_kernel<<<g2, 256, 0, stream>>>(qbf, kbf, vTf, positions, log_sigma, gbias, ns,
                                       Pbuf, rsbuf);

  // 5) combine -> bf16 attn (into xb)
  combine_kernel<<<RG_TOT * 16 / 256, 256, 0, stream>>>(Pbuf, rsbuf, xb);

  // 6) output projection (+bias) -> f32 d_out
  dim3 g3(NB * NL / 128, ND / 128);
  gemm_bf16<1><<<g3, 256, 0, stream>>>(xb, wob, b_out, nullptr, nullptr, nullptr,
                                       (float*)d_out, NH * DH);
}